// Round 1
// baseline (1174.656 us; speedup 1.0000x reference)
//
#include <hip/hip_runtime.h>

#define I_DIM 28
#define H_DIM 64
#define T_DIM 128
#define B_DIM 4096
#define OUT_DIM 10
#define NB 4   // batch elements per block (one wave per block)

__device__ __forceinline__ float fast_rcp(float v) {
    return __builtin_amdgcn_rcpf(v);
}
__device__ __forceinline__ float sigmoid_f(float v) {
    return fast_rcp(1.0f + __expf(-v));
}
__device__ __forceinline__ float tanh_f(float v) {
    // 1 - 2/(exp(2v)+1): exact at both saturation ends
    float e = __expf(2.0f * v);
    return 1.0f - 2.0f * fast_rcp(e + 1.0f);
}

__global__ __launch_bounds__(64, 1)
void lstm_fused_kernel(const float* __restrict__ x,
                       const float* __restrict__ W_ih,
                       const float* __restrict__ W_hh,
                       const float* __restrict__ b_ih,
                       const float* __restrict__ b_hh,
                       const float* __restrict__ W_out,
                       const float* __restrict__ b_out,
                       float* __restrict__ out)
{
    const int jj = threadIdx.x;        // hidden unit index 0..63
    const int b0 = blockIdx.x * NB;    // first batch element of this block

    __shared__ float hs[NB][H_DIM];    // h state, shared across the wave

    // ---- load weights into registers: lane jj owns gate rows jj, 64+jj, 128+jj, 192+jj
    float Wih_r[4][I_DIM];   // 112 regs
    float Whh_r[4][H_DIM];   // 256 regs
    float bias[4];

    #pragma unroll
    for (int k = 0; k < 4; ++k) {
        const int row = k * H_DIM + jj;
        bias[k] = b_ih[row] + b_hh[row];
        const float4* wi = (const float4*)(W_ih + row * I_DIM);
        #pragma unroll
        for (int c = 0; c < I_DIM / 4; ++c) {
            float4 v = wi[c];
            Wih_r[k][4*c+0] = v.x; Wih_r[k][4*c+1] = v.y;
            Wih_r[k][4*c+2] = v.z; Wih_r[k][4*c+3] = v.w;
        }
        const float4* wh = (const float4*)(W_hh + row * H_DIM);
        #pragma unroll
        for (int c = 0; c < H_DIM / 4; ++c) {
            float4 v = wh[c];
            Whh_r[k][4*c+0] = v.x; Whh_r[k][4*c+1] = v.y;
            Whh_r[k][4*c+2] = v.z; Whh_r[k][4*c+3] = v.w;
        }
    }

    // ---- init state
    float c_st[NB];
    #pragma unroll
    for (int b = 0; b < NB; ++b) {
        c_st[b] = 0.0f;
        hs[b][jj] = 0.0f;
    }
    __syncthreads();

    // ---- recurrence over T
    for (int t = 0; t < T_DIM; ++t) {
        float acc[NB][4];
        #pragma unroll
        for (int b = 0; b < NB; ++b) {
            #pragma unroll
            for (int k = 0; k < 4; ++k) acc[b][k] = bias[k];
        }

        // input projection: acc += W_ih[row,:] . x[b0+b, t, :]
        #pragma unroll
        for (int b = 0; b < NB; ++b) {
            const float4* xp =
                (const float4*)(x + ((size_t)(b0 + b) * T_DIM + t) * I_DIM);
            #pragma unroll
            for (int c = 0; c < I_DIM / 4; ++c) {
                float4 xv = xp[c];   // wave-uniform address -> scalar/broadcast load
                #pragma unroll
                for (int k = 0; k < 4; ++k) {
                    acc[b][k] += Wih_r[k][4*c+0] * xv.x
                               + Wih_r[k][4*c+1] * xv.y
                               + Wih_r[k][4*c+2] * xv.z
                               + Wih_r[k][4*c+3] * xv.w;
                }
            }
        }

        // recurrent projection: acc += W_hh[row,:] . h[b,:]
        #pragma unroll
        for (int b = 0; b < NB; ++b) {
            const float4* hp = (const float4*)(&hs[b][0]);
            #pragma unroll
            for (int c = 0; c < H_DIM / 4; ++c) {
                float4 hv = hp[c];   // uniform-address LDS broadcast, conflict-free
                #pragma unroll
                for (int k = 0; k < 4; ++k) {
                    acc[b][k] += Whh_r[k][4*c+0] * hv.x
                               + Whh_r[k][4*c+1] * hv.y
                               + Whh_r[k][4*c+2] * hv.z
                               + Whh_r[k][4*c+3] * hv.w;
                }
            }
        }

        __syncthreads();   // all lanes done reading hs before overwrite

        // cell update: lane jj holds all 4 gates for its hidden unit
        #pragma unroll
        for (int b = 0; b < NB; ++b) {
            float ig = sigmoid_f(acc[b][0]);
            float fg = sigmoid_f(acc[b][1]);
            float gg = tanh_f(acc[b][2]);
            float og = sigmoid_f(acc[b][3]);
            float cc = fg * c_st[b] + ig * gg;
            c_st[b] = cc;
            hs[b][jj] = og * tanh_f(cc);
        }
        __syncthreads();
    }

    // ---- output head: out[b] = h_T[b] @ W_out^T + b_out   (lanes 0..39)
    if (jj < NB * OUT_DIM) {
        const int b = jj / OUT_DIM;
        const int o = jj % OUT_DIM;
        float s = b_out[o];
        const float* wo = W_out + o * H_DIM;
        #pragma unroll
        for (int q = 0; q < H_DIM; ++q) s += hs[b][q] * wo[q];
        out[(size_t)(b0 + b) * OUT_DIM + o] = s;
    }
}

extern "C" void kernel_launch(void* const* d_in, const int* in_sizes, int n_in,
                              void* d_out, int out_size, void* d_ws, size_t ws_size,
                              hipStream_t stream) {
    const float* x     = (const float*)d_in[0];
    const float* W_ih  = (const float*)d_in[1];
    const float* W_hh  = (const float*)d_in[2];
    const float* b_ih  = (const float*)d_in[3];
    const float* b_hh  = (const float*)d_in[4];
    const float* W_out = (const float*)d_in[5];
    const float* b_out = (const float*)d_in[6];
    float* out = (float*)d_out;

    dim3 grid(B_DIM / NB);   // 1024 blocks, one wave each
    dim3 block(64);
    lstm_fused_kernel<<<grid, block, 0, stream>>>(
        x, W_ih, W_hh, b_ih, b_hh, W_out, b_out, out);
}

// Round 2
// 664.124 us; speedup vs baseline: 1.7687x; 1.7687x over previous
//
#include <hip/hip_runtime.h>

#define I_DIM 28
#define H_DIM 64
#define T_DIM 128
#define B_DIM 4096
#define OUT_DIM 10
#define NB 4     // batch elements per block
#define NW 4     // waves per block (one per gate)

__device__ __forceinline__ float fast_rcp(float v) {
    return __builtin_amdgcn_rcpf(v);
}
__device__ __forceinline__ float sigmoid_f(float v) {
    return fast_rcp(1.0f + __expf(-v));
}
__device__ __forceinline__ float tanh_f(float v) {
    float e = __expf(2.0f * v);
    return 1.0f - 2.0f * fast_rcp(e + 1.0f);
}

__global__ __launch_bounds__(256, 4)
void lstm_fused_kernel(const float* __restrict__ x,
                       const float* __restrict__ W_ih,
                       const float* __restrict__ W_hh,
                       const float* __restrict__ b_ih,
                       const float* __restrict__ b_hh,
                       const float* __restrict__ W_out,
                       const float* __restrict__ b_out,
                       float* __restrict__ out)
{
    const int tid = threadIdx.x;
    const int wv  = tid >> 6;          // gate index 0..3 (i,f,g,o)
    const int ln  = tid & 63;          // hidden-unit / row-column index
    const int b0  = blockIdx.x * NB;   // first batch element of this block

    __shared__ float hs[NB][H_DIM];          // 1 KB: h state
    __shared__ float gates[NW][NB][H_DIM];   // 4 KB: gate pre-activations

    // ---- per-lane weights: one gate row (93 floats, stays in VGPRs)
    const int row = wv * H_DIM + ln;
    float Wih_r[I_DIM];
    float Whh_r[H_DIM];
    const float bias = b_ih[row] + b_hh[row];

    {
        const float4* wi = (const float4*)(W_ih + row * I_DIM);
        #pragma unroll
        for (int c = 0; c < I_DIM / 4; ++c) {
            float4 v = wi[c];
            Wih_r[4*c+0] = v.x; Wih_r[4*c+1] = v.y;
            Wih_r[4*c+2] = v.z; Wih_r[4*c+3] = v.w;
        }
        const float4* wh = (const float4*)(W_hh + row * H_DIM);
        #pragma unroll
        for (int c = 0; c < H_DIM / 4; ++c) {
            float4 v = wh[c];
            Whh_r[4*c+0] = v.x; Whh_r[4*c+1] = v.y;
            Whh_r[4*c+2] = v.z; Whh_r[4*c+3] = v.w;
        }
    }

    // ---- init state: thread (wv,ln) owns c for (batch b0+wv, unit ln)
    float c_st = 0.0f;
    if (wv == 0) {
        #pragma unroll
        for (int b = 0; b < NB; ++b) hs[b][ln] = 0.0f;
    }
    __syncthreads();

    // ---- recurrence over T
    for (int t = 0; t < T_DIM; ++t) {
        float acc[NB];
        #pragma unroll
        for (int b = 0; b < NB; ++b) acc[b] = bias;

        // input projection (x addresses are wave-uniform -> scalar loads)
        #pragma unroll
        for (int b = 0; b < NB; ++b) {
            const float4* xp =
                (const float4*)(x + ((size_t)(b0 + b) * T_DIM + t) * I_DIM);
            #pragma unroll
            for (int c = 0; c < I_DIM / 4; ++c) {
                float4 xv = xp[c];
                acc[b] += Wih_r[4*c+0] * xv.x + Wih_r[4*c+1] * xv.y
                        + Wih_r[4*c+2] * xv.z + Wih_r[4*c+3] * xv.w;
            }
        }

        // recurrent projection (uniform LDS float4 broadcasts)
        #pragma unroll
        for (int b = 0; b < NB; ++b) {
            const float4* hp = (const float4*)(&hs[b][0]);
            #pragma unroll
            for (int c = 0; c < H_DIM / 4; ++c) {
                float4 hv = hp[c];
                acc[b] += Whh_r[4*c+0] * hv.x + Whh_r[4*c+1] * hv.y
                        + Whh_r[4*c+2] * hv.z + Whh_r[4*c+3] * hv.w;
            }
        }

        // publish gate pre-activations
        #pragma unroll
        for (int b = 0; b < NB; ++b) gates[wv][b][ln] = acc[b];
        __syncthreads();

        // pointwise cell update: thread (wv,ln) handles (b=wv, j=ln)
        {
            float ig = sigmoid_f(gates[0][wv][ln]);
            float fg = sigmoid_f(gates[1][wv][ln]);
            float gg = tanh_f  (gates[2][wv][ln]);
            float og = sigmoid_f(gates[3][wv][ln]);
            float cc = fg * c_st + ig * gg;
            c_st = cc;
            hs[wv][ln] = og * tanh_f(cc);
        }
        __syncthreads();
    }

    // ---- output head: out[b0+b, o] for 4 b x 10 o = 40 values
    if (tid < NB * OUT_DIM) {
        const int b = tid / OUT_DIM;
        const int o = tid % OUT_DIM;
        float s = b_out[o];
        const float* wo = W_out + o * H_DIM;
        #pragma unroll
        for (int q = 0; q < H_DIM; ++q) s += hs[b][q] * wo[q];
        out[(size_t)(b0 + b) * OUT_DIM + o] = s;
    }
}

extern "C" void kernel_launch(void* const* d_in, const int* in_sizes, int n_in,
                              void* d_out, int out_size, void* d_ws, size_t ws_size,
                              hipStream_t stream) {
    const float* x     = (const float*)d_in[0];
    const float* W_ih  = (const float*)d_in[1];
    const float* W_hh  = (const float*)d_in[2];
    const float* b_ih  = (const float*)d_in[3];
    const float* b_hh  = (const float*)d_in[4];
    const float* W_out = (const float*)d_in[5];
    const float* b_out = (const float*)d_in[6];
    float* out = (float*)d_out;

    dim3 grid(B_DIM / NB);   // 1024 blocks x 256 threads = 4 blocks/CU
    dim3 block(NW * 64);
    lstm_fused_kernel<<<grid, block, 0, stream>>>(
        x, W_ih, W_hh, b_ih, b_hh, W_out, b_out, out);
}

// Round 3
// 243.206 us; speedup vs baseline: 4.8299x; 2.7307x over previous
//
#include <hip/hip_runtime.h>

#define I_DIM 28
#define H_DIM 64
#define T_DIM 128
#define B_DIM 4096
#define OUT_DIM 10
#define MB 16        // batch rows per block (one 16x16x32 MFMA M-tile)
#define NTHREADS 512 // 8 waves; wave w owns gate-columns [32w, 32w+32)

typedef __attribute__((ext_vector_type(8))) short bf16x8;   // MFMA A/B frag (4 VGPR)
typedef __attribute__((ext_vector_type(4))) float f32x4;    // MFMA C/D frag
typedef __attribute__((ext_vector_type(4))) unsigned u32x4;

__device__ __forceinline__ unsigned f2bf_rne(float f) {
    unsigned u = __builtin_bit_cast(unsigned, f);
    return (u + 0x7FFFu + ((u >> 16) & 1u)) >> 16;   // round-nearest-even bf16 bits
}
__device__ __forceinline__ float bfbits2f(unsigned b16) {
    return __builtin_bit_cast(float, b16 << 16);
}
__device__ __forceinline__ unsigned ftrunc_bf(float f) {
    return __builtin_bit_cast(unsigned, f) >> 16;    // truncating bf16 bits (fine for lo term)
}

// split 8 floats into hi/lo bf16 fragments (bf16x3 emulation operands)
__device__ __forceinline__ void split_frag(const float* v, bf16x8& hi, bf16x8& lo) {
    unsigned hb[8], lb[8];
    #pragma unroll
    for (int j = 0; j < 8; ++j) {
        hb[j] = f2bf_rne(v[j]);
        float rem = v[j] - bfbits2f(hb[j]);
        lb[j] = ftrunc_bf(rem);
    }
    u32x4 hw, lw;
    #pragma unroll
    for (int i = 0; i < 4; ++i) {
        hw[i] = (hb[2*i+1] << 16) | (hb[2*i] & 0xFFFFu);
        lw[i] = (lb[2*i+1] << 16) | (lb[2*i] & 0xFFFFu);
    }
    hi = __builtin_bit_cast(bf16x8, hw);
    lo = __builtin_bit_cast(bf16x8, lw);
}

// 8 packed (hi<<16|lo) words -> hi-frag and lo-frag via byte perms
__device__ __forceinline__ void unpack_frag(uint4 a, uint4 b, bf16x8& hi, bf16x8& lo) {
    u32x4 hw, lw;
    hw[0] = __builtin_amdgcn_perm(a.y, a.x, 0x07060302u);
    hw[1] = __builtin_amdgcn_perm(a.w, a.z, 0x07060302u);
    hw[2] = __builtin_amdgcn_perm(b.y, b.x, 0x07060302u);
    hw[3] = __builtin_amdgcn_perm(b.w, b.z, 0x07060302u);
    lw[0] = __builtin_amdgcn_perm(a.y, a.x, 0x05040100u);
    lw[1] = __builtin_amdgcn_perm(a.w, a.z, 0x05040100u);
    lw[2] = __builtin_amdgcn_perm(b.y, b.x, 0x05040100u);
    lw[3] = __builtin_amdgcn_perm(b.w, b.z, 0x05040100u);
    hi = __builtin_bit_cast(bf16x8, hw);
    lo = __builtin_bit_cast(bf16x8, lw);
}

__device__ __forceinline__ float fast_rcp(float v) { return __builtin_amdgcn_rcpf(v); }
__device__ __forceinline__ float sigmoid_f(float v) { return fast_rcp(1.0f + __expf(-v)); }
__device__ __forceinline__ float tanh_f(float v) {
    float e = __expf(2.0f * v);
    return 1.0f - 2.0f * fast_rcp(e + 1.0f);
}

#define MFMA(A, B, C) __builtin_amdgcn_mfma_f32_16x16x32_bf16((A), (B), (C), 0, 0, 0)

__global__ __launch_bounds__(NTHREADS, 1)
void lstm_mfma_kernel(const float* __restrict__ x,
                      const float* __restrict__ W_ih,
                      const float* __restrict__ W_hh,
                      const float* __restrict__ b_ih,
                      const float* __restrict__ b_hh,
                      const float* __restrict__ W_out,
                      const float* __restrict__ b_out,
                      float* __restrict__ out)
{
    const int tid = threadIdx.x;
    const int wv  = tid >> 6;        // wave 0..7
    const int ln  = tid & 63;
    const int q   = ln >> 4;         // quad 0..3 (k-group within frag)
    const int cm  = ln & 15;         // A: batch row m; B: col-in-tile; C: col n
    const int b0  = blockIdx.x * MB;

    // LDS: strides picked for 16B alignment + uniform banking
    __shared__ unsigned hpack[MB][68];     // h as (bf16hi<<16)|bf16lo, row stride 68 dwords
    __shared__ float    gbuf[4][64][18];   // gates[g][unit][batch], m-stride 18 dwords

    // ---- B fragments (weights), loaded once, resident in VGPRs.
    // B[n=gn][k]: k in [0,64) -> W_hh[gn][k]; x-slab k in [0,32) -> W_ih[gn][k] (28 valid)
    bf16x8 Bhh_hi[2][2], Bhh_lo[2][2], Bih_hi[2], Bih_lo[2];
    #pragma unroll
    for (int nt = 0; nt < 2; ++nt) {
        const int gn = wv * 32 + nt * 16 + cm;   // global gate-column 0..255
        #pragma unroll
        for (int ks = 0; ks < 2; ++ks) {
            const float* wrow = W_hh + gn * H_DIM + ks * 32 + q * 8;
            float wtmp[8];
            float4 wa = *(const float4*)wrow;
            float4 wb = *(const float4*)(wrow + 4);
            wtmp[0]=wa.x; wtmp[1]=wa.y; wtmp[2]=wa.z; wtmp[3]=wa.w;
            wtmp[4]=wb.x; wtmp[5]=wb.y; wtmp[6]=wb.z; wtmp[7]=wb.w;
            split_frag(wtmp, Bhh_hi[nt][ks], Bhh_lo[nt][ks]);
        }
        {
            const float* irow = W_ih + gn * I_DIM + q * 8;   // q==3 -> offset 24 (valid, 16B aligned)
            float wtmp[8];
            float4 ia = *(const float4*)irow;
            wtmp[0]=ia.x; wtmp[1]=ia.y; wtmp[2]=ia.z; wtmp[3]=ia.w;
            if (q < 3) {
                float4 ib = *(const float4*)(irow + 4);
                wtmp[4]=ib.x; wtmp[5]=ib.y; wtmp[6]=ib.z; wtmp[7]=ib.w;
            } else {
                wtmp[4]=0.f; wtmp[5]=0.f; wtmp[6]=0.f; wtmp[7]=0.f;  // K pad 28->32
            }
            split_frag(wtmp, Bih_hi[nt], Bih_lo[nt]);
        }
    }

    // ---- update-phase ownership: thread -> unit u, batch rows m0, m0+1
    const int u  = tid & 63;
    const int m0 = 2 * (tid >> 6);
    float bias_r[4];
    #pragma unroll
    for (int g = 0; g < 4; ++g)
        bias_r[g] = b_ih[g * H_DIM + u] + b_hh[g * H_DIM + u];
    float c0 = 0.0f, c1 = 0.0f;

    // zero h state (including padding)
    for (int i = tid; i < MB * 68; i += NTHREADS) ((unsigned*)hpack)[i] = 0u;

    // ---- x prefetch: lane reads x[b0+cm][t][q*8 .. q*8+7] (28 valid, tail zero-padded)
    float4 xa, xb;
    {
        const float* p = x + ((size_t)(b0 + cm) * T_DIM + 0) * I_DIM + q * 8;
        xa = *(const float4*)p;
        if (q < 3) xb = *(const float4*)(p + 4); else xb = float4{0.f,0.f,0.f,0.f};
    }

    for (int t = 0; t < T_DIM; ++t) {
        __syncthreads();   // hpack ready (init or previous update); gbuf free to overwrite

        // ---- A fragments from h (hi/lo packed)
        uint4 h00 = *(const uint4*)&hpack[cm][q * 8];
        uint4 h01 = *(const uint4*)&hpack[cm][q * 8 + 4];
        uint4 h10 = *(const uint4*)&hpack[cm][32 + q * 8];
        uint4 h11 = *(const uint4*)&hpack[cm][32 + q * 8 + 4];
        bf16x8 Ahi0, Alo0, Ahi1, Alo1;
        unpack_frag(h00, h01, Ahi0, Alo0);
        unpack_frag(h10, h11, Ahi1, Alo1);

        // ---- A fragment from x (current, prefetched)
        bf16x8 Axhi, Axlo;
        {
            float xt[8];
            xt[0]=xa.x; xt[1]=xa.y; xt[2]=xa.z; xt[3]=xa.w;
            xt[4]=xb.x; xt[5]=xb.y; xt[6]=xb.z; xt[7]=xb.w;
            split_frag(xt, Axhi, Axlo);
        }

        // ---- prefetch x for t+1 (covers HBM/L2 latency with the rest of the iteration)
        float4 xna, xnb;
        {
            const int tn = (t + 1 < T_DIM) ? t + 1 : t;
            const float* p = x + ((size_t)(b0 + cm) * T_DIM + tn) * I_DIM + q * 8;
            xna = *(const float4*)p;
            if (q < 3) xnb = *(const float4*)(p + 4); else xnb = float4{0.f,0.f,0.f,0.f};
        }

        // ---- MFMA: G = H*Whh^T + X*Wih^T  (bf16x3: hi*hi + lo*hi + hi*lo)
        #pragma unroll
        for (int nt = 0; nt < 2; ++nt) {
            f32x4 acc = {0.f, 0.f, 0.f, 0.f};
            acc = MFMA(Ahi0, Bhh_hi[nt][0], acc);
            acc = MFMA(Ahi1, Bhh_hi[nt][1], acc);
            acc = MFMA(Alo0, Bhh_hi[nt][0], acc);
            acc = MFMA(Alo1, Bhh_hi[nt][1], acc);
            acc = MFMA(Ahi0, Bhh_lo[nt][0], acc);
            acc = MFMA(Ahi1, Bhh_lo[nt][1], acc);
            acc = MFMA(Axhi, Bih_hi[nt], acc);
            acc = MFMA(Axlo, Bih_hi[nt], acc);
            acc = MFMA(Axhi, Bih_lo[nt], acc);
            // C layout: col = cm -> gn, rows = 4q..4q+3 -> batch. Store [g][u][m].
            const int gn = wv * 32 + nt * 16 + cm;
            float* gp = &gbuf[gn >> 6][gn & 63][4 * q];
            *(float2*)(gp)     = float2{acc[0], acc[1]};
            *(float2*)(gp + 2) = float2{acc[2], acc[3]};
        }
        __syncthreads();   // gates visible

        // ---- pointwise update: thread owns cells (m0,u) and (m0+1,u); c in regs
        {
            float2 gi = *(const float2*)&gbuf[0][u][m0];
            float2 gf = *(const float2*)&gbuf[1][u][m0];
            float2 gg = *(const float2*)&gbuf[2][u][m0];
            float2 go = *(const float2*)&gbuf[3][u][m0];

            float i0 = sigmoid_f(gi.x + bias_r[0]);
            float f0 = sigmoid_f(gf.x + bias_r[1]);
            float g0 = tanh_f  (gg.x + bias_r[2]);
            float o0 = sigmoid_f(go.x + bias_r[3]);
            c0 = f0 * c0 + i0 * g0;
            float h0 = o0 * tanh_f(c0);

            float i1 = sigmoid_f(gi.y + bias_r[0]);
            float f1 = sigmoid_f(gf.y + bias_r[1]);
            float g1 = tanh_f  (gg.y + bias_r[2]);
            float o1 = sigmoid_f(go.y + bias_r[3]);
            c1 = f1 * c1 + i1 * g1;
            float h1 = o1 * tanh_f(c1);

            unsigned hi0 = f2bf_rne(h0);
            unsigned lo0 = ftrunc_bf(h0 - bfbits2f(hi0));
            hpack[m0][u] = (hi0 << 16) | (lo0 & 0xFFFFu);
            unsigned hi1 = f2bf_rne(h1);
            unsigned lo1 = ftrunc_bf(h1 - bfbits2f(hi1));
            hpack[m0 + 1][u] = (hi1 << 16) | (lo1 & 0xFFFFu);
        }

        xa = xna; xb = xnb;
    }

    __syncthreads();

    // ---- output head: 160 threads, out[b0+bb][o] = h . W_out[o] + b_out[o]
    if (tid < MB * OUT_DIM) {
        const int bb = tid / OUT_DIM;
        const int o  = tid % OUT_DIM;
        float s = b_out[o];
        const float* wo = W_out + o * H_DIM;
        #pragma unroll
        for (int uu = 0; uu < H_DIM; ++uu) {
            unsigned p = hpack[bb][uu];
            float h = bfbits2f(p >> 16) + bfbits2f((p & 0xFFFFu) << 16);
            s += h * wo[uu];
        }
        out[(size_t)(b0 + bb) * OUT_DIM + o] = s;
    }
}

extern "C" void kernel_launch(void* const* d_in, const int* in_sizes, int n_in,
                              void* d_out, int out_size, void* d_ws, size_t ws_size,
                              hipStream_t stream) {
    const float* x     = (const float*)d_in[0];
    const float* W_ih  = (const float*)d_in[1];
    const float* W_hh  = (const float*)d_in[2];
    const float* b_ih  = (const float*)d_in[3];
    const float* b_hh  = (const float*)d_in[4];
    const float* W_out = (const float*)d_in[5];
    const float* b_out = (const float*)d_in[6];
    float* out = (float*)d_out;

    dim3 grid(B_DIM / MB);        // 256 blocks -> 1 per CU
    dim3 block(NTHREADS);         // 8 waves
    lstm_mfma_kernel<<<grid, block, 0, stream>>>(
        x, W_ih, W_hh, b_ih, b_hh, W_out, b_out, out);
}

// Round 4
// 218.984 us; speedup vs baseline: 5.3641x; 1.1106x over previous
//
#include <hip/hip_runtime.h>

#define I_DIM 28
#define H_DIM 64
#define T_DIM 128
#define B_DIM 4096
#define OUT_DIM 10
#define MB 8          // batch rows per block (N-dim of transposed GEMM)
#define NTHREADS 256  // 4 waves; wave w owns gate-mtiles {w, w+4, w+8, w+12}

typedef __attribute__((ext_vector_type(8))) short bf16x8;   // MFMA A/B frag
typedef __attribute__((ext_vector_type(4))) float f32x4;    // MFMA C/D frag
typedef __attribute__((ext_vector_type(4))) unsigned u32x4;

__device__ __forceinline__ unsigned f2bf_rne(float f) {
    unsigned u = __builtin_bit_cast(unsigned, f);
    return (u + 0x7FFFu + ((u >> 16) & 1u)) >> 16;
}
__device__ __forceinline__ float bfbits2f(unsigned b16) {
    return __builtin_bit_cast(float, b16 << 16);
}
__device__ __forceinline__ unsigned ftrunc_bf(float f) {
    return __builtin_bit_cast(unsigned, f) >> 16;
}

// split 8 floats into hi/lo bf16 fragments
__device__ __forceinline__ void split_frag(const float* v, bf16x8& hi, bf16x8& lo) {
    unsigned hb[8], lb[8];
    #pragma unroll
    for (int j = 0; j < 8; ++j) {
        hb[j] = f2bf_rne(v[j]);
        float rem = v[j] - bfbits2f(hb[j]);
        lb[j] = ftrunc_bf(rem);
    }
    u32x4 hw, lw;
    #pragma unroll
    for (int i = 0; i < 4; ++i) {
        hw[i] = (hb[2*i+1] << 16) | (hb[2*i] & 0xFFFFu);
        lw[i] = (lb[2*i+1] << 16) | (lb[2*i] & 0xFFFFu);
    }
    hi = __builtin_bit_cast(bf16x8, hw);
    lo = __builtin_bit_cast(bf16x8, lw);
}

__device__ __forceinline__ float fast_rcp(float v) { return __builtin_amdgcn_rcpf(v); }
__device__ __forceinline__ float sigmoid_f(float v) { return fast_rcp(1.0f + __expf(-v)); }
__device__ __forceinline__ float tanh_f(float v) {
    float e = __expf(2.0f * v);
    return 1.0f - 2.0f * fast_rcp(e + 1.0f);
}
// lane i <- lane i-8 within each row of 16 (DPP row_shr:8)
__device__ __forceinline__ float dpp_shr8(float v) {
    int r = __builtin_amdgcn_update_dpp(0, __builtin_bit_cast(int, v),
                                        0x118, 0xF, 0xF, true);
    return __builtin_bit_cast(float, r);
}

#define MFMA(A, B, C) __builtin_amdgcn_mfma_f32_16x16x32_bf16((A), (B), (C), 0, 0, 0)

__global__ __launch_bounds__(NTHREADS, 2)
void lstm_mfma_kernel(const float* __restrict__ x,
                      const float* __restrict__ W_ih,
                      const float* __restrict__ W_hh,
                      const float* __restrict__ b_ih,
                      const float* __restrict__ b_hh,
                      const float* __restrict__ W_out,
                      const float* __restrict__ b_out,
                      float* __restrict__ out)
{
    const int tid  = threadIdx.x;
    const int wv   = tid >> 6;        // wave 0..3
    const int lane = tid & 63;
    const int q    = lane >> 4;       // quad
    const int cm   = lane & 15;
    const int b0   = blockIdx.x * MB;

    // h state in B-frag dword order, hi/lo split, double-buffered.
    // element h[u][b]: dword 64*(u>>3) + 4*b + ((u&7)>>1), halfword u&1.
    __shared__ __align__(16) unsigned hb_hi[2][512];
    __shared__ __align__(16) unsigned hb_lo[2][512];
    // x B-frags for the chunk's two timesteps, frag order (lane*4 dwords)
    __shared__ __align__(16) unsigned xb_hi[2][256];
    __shared__ __align__(16) unsigned xb_lo[2][256];

    // ---- resident A-frags (weights): wave w, gate g -> mtile w+4g,
    // A[m=cm][k=q*8+j] = W[16*(w+4g)+cm][k]
    bf16x8 Whh_hi[4][2], Whh_lo[4][2], Wih_hi[4], Wih_lo[4];
    f32x4  bias_c[4];
    #pragma unroll
    for (int g = 0; g < 4; ++g) {
        const int gn = (wv + 4 * g) * 16 + cm;     // global gate row
        #pragma unroll
        for (int kt = 0; kt < 2; ++kt) {
            const float* wr = W_hh + gn * H_DIM + kt * 32 + q * 8;
            float wt[8];
            float4 wa = *(const float4*)wr;
            float4 wb = *(const float4*)(wr + 4);
            wt[0]=wa.x; wt[1]=wa.y; wt[2]=wa.z; wt[3]=wa.w;
            wt[4]=wb.x; wt[5]=wb.y; wt[6]=wb.z; wt[7]=wb.w;
            split_frag(wt, Whh_hi[g][kt], Whh_lo[g][kt]);
        }
        {
            const float* ir = W_ih + gn * I_DIM + q * 8;
            float wt[8];
            float4 ia = *(const float4*)ir;
            wt[0]=ia.x; wt[1]=ia.y; wt[2]=ia.z; wt[3]=ia.w;
            if (q < 3) {
                float4 ib = *(const float4*)(ir + 4);
                wt[4]=ib.x; wt[5]=ib.y; wt[6]=ib.z; wt[7]=ib.w;
            } else { wt[4]=0.f; wt[5]=0.f; wt[6]=0.f; wt[7]=0.f; }
            split_frag(wt, Wih_hi[g], Wih_lo[g]);
        }
        // bias for C rows 4q+r of this mtile: unit u = 16*wv + 4q + r
        #pragma unroll
        for (int r = 0; r < 4; ++r) {
            const int row = g * H_DIM + wv * 16 + 4 * q + r;
            bias_c[g][r] = b_ih[row] + b_hh[row];
        }
    }

    // zero h buffers (cols b=8..15 stay 0 forever)
    for (int i = tid; i < 1024; i += NTHREADS) {
        ((unsigned*)hb_hi)[i] = 0u;
        ((unsigned*)hb_lo)[i] = 0u;
    }

    // ---- x loader (waves 0,1 handle t = 2*chunk + wv)
    auto load_x = [&](int t, float4& xa, float4& xb) {
        if (cm < MB) {
            const float* p = x + ((size_t)(b0 + cm) * T_DIM + t) * I_DIM + q * 8;
            xa = *(const float4*)p;
            if (q < 3) xb = *(const float4*)(p + 4);
            else       xb = float4{0.f, 0.f, 0.f, 0.f};
        } else {
            xa = float4{0.f, 0.f, 0.f, 0.f};
            xb = float4{0.f, 0.f, 0.f, 0.f};
        }
    };

    float4 xa_cur{0,0,0,0}, xb_cur{0,0,0,0};
    if (wv < 2) load_x(wv, xa_cur, xb_cur);

    float2 c_st = {0.f, 0.f};   // cell state for this lane's 2 cells
    const int hdw = 64 * (2 * wv + (q >> 1)) + 4 * (cm & 7)
                  + 2 * (q & 1) + (cm >> 3);   // h write dword

    for (int ch = 0; ch < T_DIM / 2; ++ch) {
        // prefetch next chunk's x, then split+store current
        float4 xa_nxt{0,0,0,0}, xb_nxt{0,0,0,0};
        if (wv < 2) {
            int tn = 2 * ch + 2 + wv;
            if (tn > T_DIM - 1) tn = T_DIM - 1;
            load_x(tn, xa_nxt, xb_nxt);
            float xt[8];
            xt[0]=xa_cur.x; xt[1]=xa_cur.y; xt[2]=xa_cur.z; xt[3]=xa_cur.w;
            xt[4]=xb_cur.x; xt[5]=xb_cur.y; xt[6]=xb_cur.z; xt[7]=xb_cur.w;
            bf16x8 xhi, xlo;
            split_frag(xt, xhi, xlo);
            *(u32x4*)&xb_hi[wv][lane * 4] = __builtin_bit_cast(u32x4, xhi);
            *(u32x4*)&xb_lo[wv][lane * 4] = __builtin_bit_cast(u32x4, xlo);
        }
        __syncthreads();   // xbuf visible; also orders prev step-1 h writes

        // xw = Wih * x^T + bias for both timesteps (stays in registers)
        f32x4 xw[2][4];
        #pragma unroll
        for (int tt = 0; tt < 2; ++tt) {
            bf16x8 Xhi = __builtin_bit_cast(bf16x8, *(u32x4*)&xb_hi[tt][lane * 4]);
            bf16x8 Xlo = __builtin_bit_cast(bf16x8, *(u32x4*)&xb_lo[tt][lane * 4]);
            #pragma unroll
            for (int g = 0; g < 4; ++g) {
                f32x4 a = MFMA(Wih_hi[g], Xhi, bias_c[g]);
                a = MFMA(Wih_lo[g], Xhi, a);
                a = MFMA(Wih_hi[g], Xlo, a);
                xw[tt][g] = a;
            }
        }

        // two recurrence steps: tt=0 reads hb[0] writes hb[1]; tt=1 reverse
        #pragma unroll
        for (int tt = 0; tt < 2; ++tt) {
            const int rb = tt, wb = tt ^ 1;
            if (tt == 1) __syncthreads();   // h(t) writes visible

            bf16x8 Hhi0 = __builtin_bit_cast(bf16x8, *(u32x4*)&hb_hi[rb][lane * 4]);
            bf16x8 Hhi1 = __builtin_bit_cast(bf16x8, *(u32x4*)&hb_hi[rb][256 + lane * 4]);
            bf16x8 Hlo0 = __builtin_bit_cast(bf16x8, *(u32x4*)&hb_lo[rb][lane * 4]);
            bf16x8 Hlo1 = __builtin_bit_cast(bf16x8, *(u32x4*)&hb_lo[rb][256 + lane * 4]);

            f32x4 acc[4];
            #pragma unroll
            for (int g = 0; g < 4; ++g) {
                f32x4 a = MFMA(Whh_hi[g][0], Hhi0, xw[tt][g]);
                a = MFMA(Whh_hi[g][1], Hhi1, a);
                a = MFMA(Whh_lo[g][0], Hhi0, a);
                a = MFMA(Whh_lo[g][1], Hhi1, a);
                a = MFMA(Whh_hi[g][0], Hlo0, a);
                a = MFMA(Whh_hi[g][1], Hlo1, a);
                acc[g] = a;
            }

            // redistribute: lanes cm>=8 take rows 2,3 from lane-8
            float gv[4][2];
            #pragma unroll
            for (int g = 0; g < 4; ++g) {
                float a2 = dpp_shr8(acc[g][2]);
                float a3 = dpp_shr8(acc[g][3]);
                gv[g][0] = (cm < 8) ? acc[g][0] : a2;
                gv[g][1] = (cm < 8) ? acc[g][1] : a3;
            }

            // update 2 cells; write h split hi/lo packed (2 bf16 per dword)
            unsigned hw = 0, lw = 0;
            #pragma unroll
            for (int rr = 0; rr < 2; ++rr) {
                float ig = sigmoid_f(gv[0][rr]);
                float fg = sigmoid_f(gv[1][rr]);
                float gg = tanh_f  (gv[2][rr]);
                float og = sigmoid_f(gv[3][rr]);
                float cc = fg * (rr ? c_st.y : c_st.x) + ig * gg;
                if (rr) c_st.y = cc; else c_st.x = cc;
                float hh = og * tanh_f(cc);
                unsigned hib = f2bf_rne(hh);
                unsigned lob = ftrunc_bf(hh - bfbits2f(hib));
                hw |= (hib & 0xFFFFu) << (16 * rr);
                lw |= (lob & 0xFFFFu) << (16 * rr);
            }
            hb_hi[wb][hdw] = hw;
            hb_lo[wb][hdw] = lw;
        }
        xa_cur = xa_nxt; xb_cur = xb_nxt;
    }

    __syncthreads();

    // ---- output head: final h is in hb[0]
    if (tid < MB * OUT_DIM) {
        const int bb = tid / OUT_DIM;
        const int o  = tid % OUT_DIM;
        float s = b_out[o];
        const float* wo = W_out + o * H_DIM;
        #pragma unroll
        for (int u = 0; u < H_DIM; ++u) {
            const int dw = 64 * (u >> 3) + 4 * bb + ((u & 7) >> 1);
            const int sh = (u & 1) * 16;
            float h = bfbits2f((hb_hi[0][dw] >> sh) & 0xFFFFu)
                    + bfbits2f((hb_lo[0][dw] >> sh) & 0xFFFFu);
            s += h * wo[u];
        }
        out[(size_t)(b0 + bb) * OUT_DIM + o] = s;
    }
}

extern "C" void kernel_launch(void* const* d_in, const int* in_sizes, int n_in,
                              void* d_out, int out_size, void* d_ws, size_t ws_size,
                              hipStream_t stream) {
    const float* x     = (const float*)d_in[0];
    const float* W_ih  = (const float*)d_in[1];
    const float* W_hh  = (const float*)d_in[2];
    const float* b_ih  = (const float*)d_in[3];
    const float* b_hh  = (const float*)d_in[4];
    const float* W_out = (const float*)d_in[5];
    const float* b_out = (const float*)d_in[6];
    float* out = (float*)d_out;

    dim3 grid(B_DIM / MB);    // 512 blocks -> 2 per CU
    dim3 block(NTHREADS);     // 4 waves
    lstm_mfma_kernel<<<grid, block, 0, stream>>>(
        x, W_ih, W_hh, b_ih, b_hh, W_out, b_out, out);
}